// Round 9
// baseline (100.736 us; speedup 1.0000x reference)
//
#include <hip/hip_runtime.h>

// ProteinMapper round 9: 8 threads per residue, one per rigid group.
// Rationale (r5 counters: VALU 13%, HBM 22%, conflicts 0, occ 19%): the
// thread-per-residue kernel kept 96+ live floats (G[8][12]) against a 96-VGPR
// allocation -> compiler spilled; per-atom cndmask tree re-read all 8 frames
// (~1300 scratch reads/thread at L2 latency) with only 2 waves/SIMD to hide it.
// Now: thread g builds ONLY frame g (12 regs), shares via LDS frame buffer,
// threads 5-7 compose their own prefix chains, each thread maps <=2 atoms with
// runtime-indexed ds_read_b128. No big register array, no scratch, 3x TLP.

constexpr int NRES_TOTAL = 64 * 2048;     // 131072 residues
constexpr int NRT = 21;                   // restypes
constexpr int NG  = 8;                    // groups
constexpr int NA  = 14;                   // atoms
constexpr int BLK = 512;
constexpr int RPB = BLK / NG;             // 64 residues per block
constexpr int RIG_STRIDE = 100;           // floats; 400B: 16B-aligned, %32=4

__global__ __launch_bounds__(512) void protein_mapper_kernel(
    const float* __restrict__ bb_rots,        // (B,L,3,3)
    const float* __restrict__ bb_trans,       // (B,L,3)
    const float* __restrict__ angles,         // (B,L,7,2)
    const int*   __restrict__ aatype,         // (B,L)
    const float* __restrict__ default_frames, // (21,8,4,4)
    const int*   __restrict__ group_idx,      // (21,14)
    const float* __restrict__ atom_mask,      // (21,14)
    const float* __restrict__ lit_positions,  // (21,14,3)
    float* __restrict__ out)                  // (B,L,14,3)
{
    // ---- LDS: transposed tables [element][aa] + per-residue frame buffer ----
    __shared__ float s_frames[128 * NRT];         // 10752 B
    __shared__ int   s_gidx[NA * NRT];            //  1176 B
    __shared__ float s_mask[NA * NRT];            //  1176 B
    __shared__ float s_lit[NA * 3 * NRT];         //  3528 B
    __shared__ float s_rig[RPB * RIG_STRIDE];     // 25600 B  [res][group*12+e]

    const int t = threadIdx.x;
    for (int n = t; n < NRT * 128; n += BLK) {
        const int aa = n / 128, j = n % 128;
        s_frames[j * NRT + aa] = default_frames[n];
    }
    for (int n = t; n < NRT * NA; n += BLK) {
        const int aa = n / NA, a = n % NA;
        s_gidx[a * NRT + aa] = group_idx[n];
        s_mask[a * NRT + aa] = atom_mask[n];
    }
    for (int n = t; n < NRT * NA * 3; n += BLK) {
        const int aa = n / (NA * 3), k = n % (NA * 3);
        s_lit[k * NRT + aa] = lit_positions[n];
    }

    const int lres = t >> 3;                       // residue within block
    const int sub  = t & 7;                        // my group
    const int res  = blockIdx.x * RPB + lres;      // grid exact: no OOB
    const int aa   = aatype[res];

    // my group's sin/cos (group 0 = identity)
    float sg_ = 0.0f, cg_ = 1.0f;
    if (sub != 0) {
        const float2 sc = *reinterpret_cast<const float2*>(
            angles + (size_t)res * 14 + (size_t)(sub - 1) * 2);
        sg_ = sc.x; cg_ = sc.y;
    }
    __syncthreads();   // tables staged

    // ---- build MY local frame F (12 floats: R row-major, then t) ----
    float F[12];
    #pragma unroll
    for (int r = 0; r < 3; ++r) {
        const float a0 = s_frames[(sub * 16 + r * 4 + 0) * NRT + aa];
        const float a1 = s_frames[(sub * 16 + r * 4 + 1) * NRT + aa];
        const float a2 = s_frames[(sub * 16 + r * 4 + 2) * NRT + aa];
        const float a3 = s_frames[(sub * 16 + r * 4 + 3) * NRT + aa];
        F[r * 3 + 0] = a0;
        F[r * 3 + 1] = cg_ * a1 + sg_ * a2;
        F[r * 3 + 2] = cg_ * a2 - sg_ * a1;
        F[9 + r]     = a3;
    }

    // write local frame to the residue's LDS slot (3x ds_write_b128)
    float* rig = s_rig + lres * RIG_STRIDE;
    {
        float4* dst = reinterpret_cast<float4*>(rig + sub * 12);
        float4 w0; w0.x = F[0]; w0.y = F[1];  w0.z = F[2];  w0.w = F[3];
        float4 w1; w1.x = F[4]; w1.y = F[5];  w1.z = F[6];  w1.w = F[7];
        float4 w2; w2.x = F[8]; w2.y = F[9];  w2.z = F[10]; w2.w = F[11];
        dst[0] = w0; dst[1] = w1; dst[2] = w2;
    }
    __syncthreads();   // all locals visible

    // ---- threads 5..7: compose own prefix chain F4∘F5(∘F6(∘F7)) ----
    float P[12];
    if (sub >= 5) {
        const float4* f4 = reinterpret_cast<const float4*>(rig + 4 * 12);
        float4 p0 = f4[0], p1 = f4[1], p2 = f4[2];
        P[0]=p0.x; P[1]=p0.y; P[2]=p0.z; P[3]=p0.w;
        P[4]=p1.x; P[5]=p1.y; P[6]=p1.z; P[7]=p1.w;
        P[8]=p2.x; P[9]=p2.y; P[10]=p2.z; P[11]=p2.w;
        for (int g = 5; g <= sub; ++g) {
            const float4* fg = reinterpret_cast<const float4*>(rig + g * 12);
            const float4 l0 = fg[0], l1 = fg[1], l2 = fg[2];
            const float L[12] = {l0.x,l0.y,l0.z,l0.w,l1.x,l1.y,l1.z,l1.w,
                                 l2.x,l2.y,l2.z,l2.w};
            float Q[12];
            #pragma unroll
            for (int r = 0; r < 3; ++r) {
                const float p0_ = P[r*3+0], p1_ = P[r*3+1], p2_ = P[r*3+2];
                #pragma unroll
                for (int c = 0; c < 3; ++c)
                    Q[r*3+c] = p0_ * L[c] + p1_ * L[3+c] + p2_ * L[6+c];
                Q[9+r] = p0_ * L[9] + p1_ * L[10] + p2_ * L[11] + P[9+r];
            }
            #pragma unroll
            for (int k = 0; k < 12; ++k) P[k] = Q[k];
        }
    }
    __syncthreads();   // all compose READS of locals complete
    if (sub >= 5) {
        float4* dst = reinterpret_cast<float4*>(rig + sub * 12);
        float4 w0; w0.x = P[0]; w0.y = P[1];  w0.z = P[2];  w0.w = P[3];
        float4 w1; w1.x = P[4]; w1.y = P[5];  w1.z = P[6];  w1.w = P[7];
        float4 w2; w2.x = P[8]; w2.y = P[9];  w2.z = P[10]; w2.w = P[11];
        dst[0] = w0; dst[1] = w1; dst[2] = w2;
    }
    __syncthreads();   // frame buffer final

    // ---- backbone frame (per residue; 8-way redundant load, L1-served) ----
    const float* br = bb_rots + (size_t)res * 9;
    const float b00 = br[0], b01 = br[1], b02 = br[2];
    const float b10 = br[3], b11 = br[4], b12 = br[5];
    const float b20 = br[6], b21 = br[7], b22 = br[8];
    const float* btp = bb_trans + (size_t)res * 3;
    const float bt0 = btp[0], bt1 = btp[1], bt2 = btp[2];

    // ---- my atoms: a = sub and sub+8 (sub<6) ----
    #pragma unroll
    for (int k = 0; k < 2; ++k) {
        const int a = sub + k * 8;
        if (a < NA) {
            const int   ga = s_gidx[a * NRT + aa];
            const float m_ = s_mask[a * NRT + aa];
            const float lx = s_lit[(a * 3 + 0) * NRT + aa];
            const float ly = s_lit[(a * 3 + 1) * NRT + aa];
            const float lz = s_lit[(a * 3 + 2) * NRT + aa];
            const float4* fp = reinterpret_cast<const float4*>(rig + ga * 12);
            const float4 f0 = fp[0], f1 = fp[1], f2 = fp[2];
            // f0 = R00 R01 R02 R10 ; f1 = R11 R12 R20 R21 ; f2 = R22 t0 t1 t2
            const float px = f0.x * lx + f0.y * ly + f0.z * lz + f2.y;
            const float py = f0.w * lx + f1.x * ly + f1.y * lz + f2.z;
            const float pz = f1.z * lx + f1.w * ly + f2.x * lz + f2.w;
            float* op = out + (size_t)res * (NA * 3) + a * 3;
            op[0] = (b00 * px + b01 * py + b02 * pz + bt0) * m_;
            op[1] = (b10 * px + b11 * py + b12 * pz + bt1) * m_;
            op[2] = (b20 * px + b21 * py + b22 * pz + bt2) * m_;
        }
    }
}

extern "C" void kernel_launch(void* const* d_in, const int* in_sizes, int n_in,
                              void* d_out, int out_size, void* d_ws, size_t ws_size,
                              hipStream_t stream) {
    const float* bb_rots        = (const float*)d_in[0];
    const float* bb_trans       = (const float*)d_in[1];
    const float* angles         = (const float*)d_in[2];
    const int*   aatype         = (const int*)d_in[3];
    const float* default_frames = (const float*)d_in[4];
    const int*   group_idx      = (const int*)d_in[5];
    const float* atom_mask      = (const float*)d_in[6];
    const float* lit_positions  = (const float*)d_in[7];
    float* out = (float*)d_out;

    const int blocks = NRES_TOTAL / RPB;   // 2048, exact
    protein_mapper_kernel<<<blocks, BLK, 0, stream>>>(
        bb_rots, bb_trans, angles, aatype,
        default_frames, group_idx, atom_mask, lit_positions, out);
}

// Round 10
// 96.777 us; speedup vs baseline: 1.0409x; 1.0409x over previous
//
#include <hip/hip_runtime.h>

// ProteinMapper round 10: group-major scan with local-position accumulator.
// Theory: r5's 45us dispatch = partial spill of the 96-float G[8][12] array
// (VGPR_Count=96 < live set; cndmask tree re-read all frames per atom) at L2
// latency with only 2 waves/SIMD. r8's (256,2) never tested this (cap not
// binding). This kernel NEVER holds more than ONE composed frame: rolled
// wave-uniform g-loop keeps C[12] + p[42] accumulator; per (g,atom) the
// selected local position is chosen by cndmask. Peak live ~110 regs -> no
// spill; ~5KB code; bb transform deferred to a single per-atom epilogue.

constexpr int NRES_TOTAL = 64 * 2048;     // 131072 residues
constexpr int NRT = 21;                   // restypes
constexpr int NG  = 8;                    // groups
constexpr int NA  = 14;                   // atoms

__global__ __launch_bounds__(256, 2) void protein_mapper_kernel(
    const float* __restrict__ bb_rots,        // (B,L,3,3)
    const float* __restrict__ bb_trans,       // (B,L,3)
    const float* __restrict__ angles,         // (B,L,7,2)
    const int*   __restrict__ aatype,         // (B,L)
    const float* __restrict__ default_frames, // (21,8,4,4)
    const int*   __restrict__ group_idx,      // (21,14)
    const float* __restrict__ atom_mask,      // (21,14)
    const float* __restrict__ lit_positions,  // (21,14,3)
    float* __restrict__ out)                  // (B,L,14,3)
{
    // ---- LDS tables, transposed [element][aa] (conflict-free, validated r5) ----
    __shared__ float s_frames[128 * NRT];     // 10752 B
    __shared__ int   s_gidx[NA * NRT];        //  1176 B
    __shared__ float s_mask[NA * NRT];        //  1176 B
    __shared__ float s_lit[NA * 3 * NRT];     //  3528 B

    const int i  = blockIdx.x * 256 + threadIdx.x;   // grid exact
    // issue per-residue loads early (hide under staging)
    const int aa = aatype[i];
    float sv[NG], cv[NG];
    sv[0] = 0.0f; cv[0] = 1.0f;
    {
        const float2* angp = reinterpret_cast<const float2*>(angles + (size_t)i * 14);
        #pragma unroll
        for (int g = 1; g < NG; ++g) {
            float2 sc = angp[g - 1];
            sv[g] = sc.x;   // sin
            cv[g] = sc.y;   // cos
        }
    }

    for (int n = threadIdx.x; n < NRT * 128; n += 256) {
        const int a_ = n / 128, j = n % 128;
        s_frames[j * NRT + a_] = default_frames[n];
    }
    for (int n = threadIdx.x; n < NRT * NA; n += 256) {
        const int a_ = n / NA, a = n % NA;
        s_gidx[a * NRT + a_] = group_idx[n];
        s_mask[a * NRT + a_] = atom_mask[n];
    }
    for (int n = threadIdx.x; n < NRT * NA * 3; n += 256) {
        const int a_ = n / (NA * 3), k = n % (NA * 3);
        s_lit[k * NRT + a_] = lit_positions[n];
    }
    __syncthreads();

    // per-atom group ids in registers (static indexing)
    int ga[NA];
    #pragma unroll
    for (int a = 0; a < NA; ++a) ga[a] = s_gidx[a * NRT + aa];

    // local-position accumulator
    float p[NA * 3];
    #pragma unroll
    for (int k = 0; k < NA * 3; ++k) p[k] = 0.0f;

    // ---- rolled, wave-uniform group loop: only C[12] persists ----
    float C[12];
    #pragma clang loop unroll(disable)
    for (int g = 0; g < NG; ++g) {
        // select this group's (s,c) without dynamic register indexing
        float sg_ = sv[0], cg_ = cv[0];
        sg_ = (g == 1) ? sv[1] : sg_;  cg_ = (g == 1) ? cv[1] : cg_;
        sg_ = (g == 2) ? sv[2] : sg_;  cg_ = (g == 2) ? cv[2] : cg_;
        sg_ = (g == 3) ? sv[3] : sg_;  cg_ = (g == 3) ? cv[3] : cg_;
        sg_ = (g == 4) ? sv[4] : sg_;  cg_ = (g == 4) ? cv[4] : cg_;
        sg_ = (g == 5) ? sv[5] : sg_;  cg_ = (g == 5) ? cv[5] : cg_;
        sg_ = (g == 6) ? sv[6] : sg_;  cg_ = (g == 6) ? cv[6] : cg_;
        sg_ = (g == 7) ? sv[7] : sg_;  cg_ = (g == 7) ? cv[7] : cg_;

        // local frame L = dF[:3,:3] @ rotx(s,c), Lt = dF[:3,3]
        float L[12];
        #pragma unroll
        for (int r = 0; r < 3; ++r) {
            const float a0 = s_frames[(g * 16 + r * 4 + 0) * NRT + aa];
            const float a1 = s_frames[(g * 16 + r * 4 + 1) * NRT + aa];
            const float a2 = s_frames[(g * 16 + r * 4 + 2) * NRT + aa];
            const float a3 = s_frames[(g * 16 + r * 4 + 3) * NRT + aa];
            L[r * 3 + 0] = a0;
            L[r * 3 + 1] = cg_ * a1 + sg_ * a2;
            L[r * 3 + 2] = cg_ * a2 - sg_ * a1;
            L[9 + r]     = a3;
        }

        if (g < 5) {
            #pragma unroll
            for (int k = 0; k < 12; ++k) C[k] = L[k];
        } else {
            // C <- C_prev ∘ L   (chain base at g=5 is C_prev = L4)
            float Q[12];
            #pragma unroll
            for (int r = 0; r < 3; ++r) {
                const float c0 = C[r * 3 + 0], c1 = C[r * 3 + 1], c2 = C[r * 3 + 2];
                #pragma unroll
                for (int c = 0; c < 3; ++c)
                    Q[r * 3 + c] = c0 * L[c] + c1 * L[3 + c] + c2 * L[6 + c];
                Q[9 + r] = c0 * L[9] + c1 * L[10] + c2 * L[11] + C[9 + r];
            }
            #pragma unroll
            for (int k = 0; k < 12; ++k) C[k] = Q[k];
        }

        // atoms whose group == g take their local position from C
        #pragma unroll
        for (int a = 0; a < NA; ++a) {
            const bool sel = (ga[a] == g);
            const float lx = s_lit[(a * 3 + 0) * NRT + aa];
            const float ly = s_lit[(a * 3 + 1) * NRT + aa];
            const float lz = s_lit[(a * 3 + 2) * NRT + aa];
            const float rx = C[0] * lx + C[1] * ly + C[2] * lz + C[9];
            const float ry = C[3] * lx + C[4] * ly + C[5] * lz + C[10];
            const float rz = C[6] * lx + C[7] * ly + C[8] * lz + C[11];
            p[a * 3 + 0] = sel ? rx : p[a * 3 + 0];
            p[a * 3 + 1] = sel ? ry : p[a * 3 + 1];
            p[a * 3 + 2] = sel ? rz : p[a * 3 + 2];
        }
    }

    // ---- epilogue: backbone transform + mask, float2 stores ----
    const float* br = bb_rots + (size_t)i * 9;
    const float b00 = br[0], b01 = br[1], b02 = br[2];
    const float b10 = br[3], b11 = br[4], b12 = br[5];
    const float b20 = br[6], b21 = br[7], b22 = br[8];
    const float* btp = bb_trans + (size_t)i * 3;
    const float bt0 = btp[0], bt1 = btp[1], bt2 = btp[2];

    float res[NA * 3];
    #pragma unroll
    for (int a = 0; a < NA; ++a) {
        const float m_ = s_mask[a * NRT + aa];
        const float px = p[a * 3 + 0], py = p[a * 3 + 1], pz = p[a * 3 + 2];
        res[a * 3 + 0] = (b00 * px + b01 * py + b02 * pz + bt0) * m_;
        res[a * 3 + 1] = (b10 * px + b11 * py + b12 * pz + bt1) * m_;
        res[a * 3 + 2] = (b20 * px + b21 * py + b22 * pz + bt2) * m_;
    }

    float2* op2 = reinterpret_cast<float2*>(out + (size_t)i * (NA * 3));
    #pragma unroll
    for (int k = 0; k < (NA * 3) / 2; ++k) {
        float2 v; v.x = res[2 * k + 0]; v.y = res[2 * k + 1];
        op2[k] = v;
    }
}

extern "C" void kernel_launch(void* const* d_in, const int* in_sizes, int n_in,
                              void* d_out, int out_size, void* d_ws, size_t ws_size,
                              hipStream_t stream) {
    const float* bb_rots        = (const float*)d_in[0];
    const float* bb_trans       = (const float*)d_in[1];
    const float* angles         = (const float*)d_in[2];
    const int*   aatype         = (const int*)d_in[3];
    const float* default_frames = (const float*)d_in[4];
    const int*   group_idx      = (const int*)d_in[5];
    const float* atom_mask      = (const float*)d_in[6];
    const float* lit_positions  = (const float*)d_in[7];
    float* out = (float*)d_out;

    const int blocks = NRES_TOTAL / 256;   // 512, exact
    protein_mapper_kernel<<<blocks, 256, 0, stream>>>(
        bb_rots, bb_trans, angles, aatype,
        default_frames, group_idx, atom_mask, lit_positions, out);
}